// Round 1
// baseline (13816.449 us; speedup 1.0000x reference)
//
#include <hip/hip_runtime.h>
#include <math.h>

#define S_LEN 1024
#define E_DIM 512
#define H_DIM 512
#define G3    1536   // 3*H
#define D_DIM 1024

#define NCHAIN 4
#define WPC    32    // workgroups per GRU chain (128 blocks total, <= 256 CUs -> co-resident)

// ---------------------------------------------------------------------------
// Phase 1: gi[p][t][j] = bih_p[j] + sum_k emb[sent[t],k] * Wih_p[j,k]
// Tiled fp32 GEMM, TM=TN=64, BK=32, 256 threads, 4x4 micro-tile per thread.
// ---------------------------------------------------------------------------
#define TM 64
#define TN 64
#define BK 32

__global__ __launch_bounds__(256) void gi_gemm_kernel(
    const int* __restrict__ sent, const float* __restrict__ emb,
    const float* __restrict__ Wih0, const float* __restrict__ bih0,
    const float* __restrict__ Wih1, const float* __restrict__ bih1,
    const float* __restrict__ Wih2, const float* __restrict__ bih2,
    const float* __restrict__ Wih3, const float* __restrict__ bih3,
    float* __restrict__ gi)
{
    __shared__ float As[BK][TM + 1];
    __shared__ float Bs[BK][TN + 1];
    __shared__ int   rows[TM];

    const int blocks_t = S_LEN / TM;   // 16
    const int blocks_j = G3 / TN;      // 24
    int b   = blockIdx.x;
    int p   = b / (blocks_t * blocks_j);
    int rem = b % (blocks_t * blocks_j);
    int bt  = rem / blocks_j;
    int bj  = rem % blocks_j;

    const float* Wih = (p == 0) ? Wih0 : (p == 1) ? Wih1 : (p == 2) ? Wih2 : Wih3;
    const float* bih = (p == 0) ? bih0 : (p == 1) ? bih1 : (p == 2) ? bih2 : bih3;

    int tid = threadIdx.x;
    if (tid < TM) rows[tid] = sent[bt * TM + tid];
    __syncthreads();

    int tt = (tid >> 4) * 4;   // local t offset of micro-tile
    int jj = (tid & 15) * 4;   // local j offset of micro-tile
    float acc[4][4] = {{0.f}};

    int lr = tid >> 2;         // 0..63 (row within tile)
    int lc = (tid & 3) * 8;    // 0,8,16,24 (col chunk)

    for (int k0 = 0; k0 < E_DIM; k0 += BK) {
        const float* asrc = emb + (size_t)rows[lr] * E_DIM + (k0 + lc);
        float4 a0 = *(const float4*)asrc;
        float4 a1 = *(const float4*)(asrc + 4);
        const float* bsrc = Wih + (size_t)(bj * TN + lr) * E_DIM + (k0 + lc);
        float4 b0 = *(const float4*)bsrc;
        float4 b1 = *(const float4*)(bsrc + 4);

        As[lc+0][lr]=a0.x; As[lc+1][lr]=a0.y; As[lc+2][lr]=a0.z; As[lc+3][lr]=a0.w;
        As[lc+4][lr]=a1.x; As[lc+5][lr]=a1.y; As[lc+6][lr]=a1.z; As[lc+7][lr]=a1.w;
        Bs[lc+0][lr]=b0.x; Bs[lc+1][lr]=b0.y; Bs[lc+2][lr]=b0.z; Bs[lc+3][lr]=b0.w;
        Bs[lc+4][lr]=b1.x; Bs[lc+5][lr]=b1.y; Bs[lc+6][lr]=b1.z; Bs[lc+7][lr]=b1.w;
        __syncthreads();

        #pragma unroll
        for (int kk = 0; kk < BK; ++kk) {
            float av[4], bv[4];
            #pragma unroll
            for (int e = 0; e < 4; ++e) { av[e] = As[kk][tt+e]; bv[e] = Bs[kk][jj+e]; }
            #pragma unroll
            for (int i = 0; i < 4; ++i)
                #pragma unroll
                for (int j2 = 0; j2 < 4; ++j2)
                    acc[i][j2] = fmaf(av[i], bv[j2], acc[i][j2]);
        }
        __syncthreads();
    }

    float* gout = gi + (size_t)p * S_LEN * G3;
    int jbase = bj * TN + jj;
    float bb0 = bih[jbase+0], bb1 = bih[jbase+1], bb2 = bih[jbase+2], bb3 = bih[jbase+3];
    #pragma unroll
    for (int i = 0; i < 4; ++i) {
        int t = bt * TM + tt + i;
        float4 v = make_float4(acc[i][0]+bb0, acc[i][1]+bb1, acc[i][2]+bb2, acc[i][3]+bb3);
        *(float4*)(gout + (size_t)t * G3 + jbase) = v;
    }
}

// ---------------------------------------------------------------------------
// Phase 2: 4 independent GRU recurrences, persistent kernel.
// 128 blocks x 256 threads. Block b: chain c = b/32, sub-id w = b%32.
// Block owns hidden indices [16w, 16w+16); wave wv owns 4 of them.
// All 48 Whh rows the block needs live in registers (96 floats/thread).
// Per-chain barrier: monotonically increasing agent-scope atomic counter.
// ---------------------------------------------------------------------------
__global__ __launch_bounds__(256) void gru_scan_kernel(
    const float* __restrict__ Whh0, const float* __restrict__ bhh0,
    const float* __restrict__ Whh1, const float* __restrict__ bhh1,
    const float* __restrict__ Whh2, const float* __restrict__ bhh2,
    const float* __restrict__ Whh3, const float* __restrict__ bhh3,
    const float* __restrict__ gi,
    float* __restrict__ hbuf,          // [4][2][512], zero-initialized
    unsigned int* __restrict__ flags)  // [4][16], zero-initialized
{
    int b = blockIdx.x;
    int c = b / WPC;
    int w = b % WPC;
    const float* Whh = (c==0)?Whh0:(c==1)?Whh1:(c==2)?Whh2:Whh3;
    const float* bhh = (c==0)?bhh0:(c==1)?bhh1:(c==2)?bhh2:Whh3 ? ((c==3)?bhh3:bhh2) : bhh2;
    // (clean select below; the above line is replaced)
    bhh = (c==0)?bhh0:(c==1)?bhh1:(c==2)?bhh2:bhh3;
    const float* gic = gi + (size_t)c * S_LEN * G3;
    float* hb = hbuf + c * 2 * H_DIM;
    unsigned int* flag = flags + c * 16;
    const bool fwd = ((c & 1) == 0);   // chains 0 (ctx_f) and 2 (qry_f) are forward

    int tid  = threadIdx.x;
    int wv   = tid >> 6;
    int lane = tid & 63;
    int base_i = w * 16 + wv * 4;

    // Load Whh fragment: wreg[g][m][e] = Whh[g*512 + base_i + m][lane*8 + e]
    float wreg[3][4][8];
    #pragma unroll
    for (int g = 0; g < 3; ++g)
        #pragma unroll
        for (int m = 0; m < 4; ++m) {
            const float* src = Whh + (size_t)(g * H_DIM + base_i + m) * H_DIM + lane * 8;
            float4 v0 = *(const float4*)src;
            float4 v1 = *(const float4*)(src + 4);
            wreg[g][m][0]=v0.x; wreg[g][m][1]=v0.y; wreg[g][m][2]=v0.z; wreg[g][m][3]=v0.w;
            wreg[g][m][4]=v1.x; wreg[g][m][5]=v1.y; wreg[g][m][6]=v1.z; wreg[g][m][7]=v1.w;
        }

    int my_i = base_i + lane;   // meaningful for lane < 4
    float bh_r=0.f, bh_z=0.f, bh_n=0.f;
    float gr=0.f, gz=0.f, gn=0.f;
    if (lane < 4) {
        bh_r = bhh[my_i]; bh_z = bhh[H_DIM + my_i]; bh_n = bhh[2*H_DIM + my_i];
        int t0 = fwd ? 0 : (S_LEN - 1);
        const float* g0 = gic + (size_t)t0 * G3;
        gr = g0[my_i]; gz = g0[H_DIM + my_i]; gn = g0[2*H_DIM + my_i];
    }

    for (int s = 0; s < S_LEN; ++s) {
        const float* hprev = hb + ((s & 1) ? H_DIM : 0);
        float*       hnext = hb + ((s & 1) ? 0 : H_DIM);

        float4 h0  = *(const float4*)(hprev + lane * 8);
        float4 h1v = *(const float4*)(hprev + lane * 8 + 4);
        float hf[8] = {h0.x,h0.y,h0.z,h0.w,h1v.x,h1v.y,h1v.z,h1v.w};

        float acc[3][4];
        #pragma unroll
        for (int g = 0; g < 3; ++g)
            #pragma unroll
            for (int m = 0; m < 4; ++m) {
                float a = 0.f;
                #pragma unroll
                for (int e = 0; e < 8; ++e) a = fmaf(wreg[g][m][e], hf[e], a);
                acc[g][m] = a;
            }
        #pragma unroll
        for (int off = 32; off >= 1; off >>= 1)
            #pragma unroll
            for (int g = 0; g < 3; ++g)
                #pragma unroll
                for (int m = 0; m < 4; ++m)
                    acc[g][m] += __shfl_xor(acc[g][m], off, 64);

        if (lane < 4) {
            float ar = (lane==0)?acc[0][0]:(lane==1)?acc[0][1]:(lane==2)?acc[0][2]:acc[0][3];
            float az = (lane==0)?acc[1][0]:(lane==1)?acc[1][1]:(lane==2)?acc[1][2]:acc[1][3];
            float an = (lane==0)?acc[2][0]:(lane==1)?acc[2][1]:(lane==2)?acc[2][2]:acc[2][3];
            float hv = hprev[my_i];
            float rr = 1.f / (1.f + expf(-(gr + ar + bh_r)));
            float zz = 1.f / (1.f + expf(-(gz + az + bh_z)));
            float nn = tanhf(gn + rr * (an + bh_n));
            hnext[my_i] = (1.f - zz) * nn + zz * hv;
        }
        // Prefetch next step's gi (independent of recurrence — off critical path)
        if (lane < 4 && s + 1 < S_LEN) {
            int tn = fwd ? (s + 1) : (S_LEN - 2 - s);
            const float* gnx = gic + (size_t)tn * G3;
            gr = gnx[my_i]; gz = gnx[H_DIM + my_i]; gn = gnx[2*H_DIM + my_i];
        }

        __threadfence();       // agent-scope: publish h_next before arrive
        __syncthreads();
        if (tid == 0) {
            __hip_atomic_fetch_add(flag, 1u, __ATOMIC_RELEASE, __HIP_MEMORY_SCOPE_AGENT);
            if (s + 1 < S_LEN) {
                unsigned int target = (unsigned int)WPC * (unsigned int)(s + 1);
                while (__hip_atomic_load(flag, __ATOMIC_ACQUIRE, __HIP_MEMORY_SCOPE_AGENT) < target)
                    __builtin_amdgcn_s_sleep(1);
            }
        }
        __syncthreads();
    }
}

// ---------------------------------------------------------------------------
// Phase 3a: h1 = relu(d1_w @ rep + d1_b); rep[j] = hbuf[j>>9][0][j&511]
// 256 blocks x 256 threads; one wave per output row.
// ---------------------------------------------------------------------------
__global__ __launch_bounds__(256) void dense1_kernel(
    const float* __restrict__ d1w, const float* __restrict__ d1b,
    const float* __restrict__ hbuf, float* __restrict__ h1)
{
    int wv = threadIdx.x >> 6, lane = threadIdx.x & 63;
    int row = blockIdx.x * 4 + wv;
    const float* wr = d1w + (size_t)row * (4 * H_DIM);
    float sum = 0.f;
    #pragma unroll
    for (int q = 0; q < 32; ++q) {
        int j = lane + q * 64;
        int cc = j >> 9;
        sum = fmaf(wr[j], hbuf[cc * 2 * H_DIM + (j & 511)], sum);
    }
    #pragma unroll
    for (int off = 32; off >= 1; off >>= 1) sum += __shfl_xor(sum, off, 64);
    if (lane == 0) h1[row] = fmaxf(sum + d1b[row], 0.f);
}

// Phase 3b: out = sigmoid(d2_w @ h1 + d2_b), one block.
__global__ __launch_bounds__(256) void dense2_kernel(
    const float* __restrict__ d2w, const float* __restrict__ d2b,
    const float* __restrict__ h1, float* __restrict__ out)
{
    __shared__ float red[4];
    int tid = threadIdx.x, lane = tid & 63, wv = tid >> 6;
    float sum = 0.f;
    #pragma unroll
    for (int q = 0; q < 4; ++q) { int j = tid + q * 256; sum = fmaf(d2w[j], h1[j], sum); }
    #pragma unroll
    for (int off = 32; off >= 1; off >>= 1) sum += __shfl_xor(sum, off, 64);
    if (lane == 0) red[wv] = sum;
    __syncthreads();
    if (tid == 0) {
        float t = red[0] + red[1] + red[2] + red[3] + d2b[0];
        out[0] = 1.f / (1.f + expf(-t));
    }
}

// ---------------------------------------------------------------------------
extern "C" void kernel_launch(void* const* d_in, const int* in_sizes, int n_in,
                              void* d_out, int out_size, void* d_ws, size_t ws_size,
                              hipStream_t stream) {
    const int*   sent = (const int*)d_in[0];
    const float* emb  = (const float*)d_in[1];
    const float* Wih[4], *Whh[4], *bih[4], *bhh[4];
    for (int p = 0; p < 4; ++p) {
        Wih[p] = (const float*)d_in[2 + 4*p + 0];
        Whh[p] = (const float*)d_in[2 + 4*p + 1];
        bih[p] = (const float*)d_in[2 + 4*p + 2];
        bhh[p] = (const float*)d_in[2 + 4*p + 3];
    }
    const float* d1w = (const float*)d_in[18];
    const float* d1b = (const float*)d_in[19];
    const float* d2w = (const float*)d_in[20];
    const float* d2b = (const float*)d_in[21];
    float* out = (float*)d_out;

    // Workspace layout (floats):
    //   gi    : 4*1024*1536 = 6291456
    //   hbuf  : 4*2*512     = 4096     (zero-init)
    //   flags : 64 uints               (zero-init)
    //   h1    : 1024
    float* ws    = (float*)d_ws;
    float* gi    = ws;
    float* hbuf  = ws + (size_t)NCHAIN * S_LEN * G3;
    unsigned int* flags = (unsigned int*)(hbuf + NCHAIN * 2 * H_DIM);
    float* h1    = (float*)(flags + 64);

    hipMemsetAsync(hbuf, 0, (NCHAIN * 2 * H_DIM + 64) * sizeof(float), stream);

    gi_gemm_kernel<<<NCHAIN * (S_LEN/TM) * (G3/TN), 256, 0, stream>>>(
        sent, emb,
        Wih[0], bih[0], Wih[1], bih[1], Wih[2], bih[2], Wih[3], bih[3], gi);

    gru_scan_kernel<<<NCHAIN * WPC, 256, 0, stream>>>(
        Whh[0], bhh[0], Whh[1], bhh[1], Whh[2], bhh[2], Whh[3], bhh[3],
        gi, hbuf, flags);

    dense1_kernel<<<D_DIM / 4, 256, 0, stream>>>(d1w, d1b, hbuf, h1);
    dense2_kernel<<<1, 256, 0, stream>>>(d2w, d2b, h1, out);
}

// Round 2
// 2810.205 us; speedup vs baseline: 4.9165x; 4.9165x over previous
//
#include <hip/hip_runtime.h>
#include <math.h>

typedef unsigned long long u64;

#define S_LEN 1024
#define E_DIM 512
#define H_DIM 512
#define G3    1536   // 3*H
#define D_DIM 1024

#define NCHAIN 4
#define WPC    32    // workgroups per GRU chain (128 blocks total, co-resident on 256 CUs)

// ---------------------------------------------------------------------------
// Phase 1: gi[p][t][j] = bih_p[j] + sum_k emb[sent[t],k] * Wih_p[j,k]
// Tiled fp32 GEMM, TM=TN=64, BK=32, 256 threads, 4x4 micro-tile per thread.
// ---------------------------------------------------------------------------
#define TM 64
#define TN 64
#define BK 32

__global__ __launch_bounds__(256) void gi_gemm_kernel(
    const int* __restrict__ sent, const float* __restrict__ emb,
    const float* __restrict__ Wih0, const float* __restrict__ bih0,
    const float* __restrict__ Wih1, const float* __restrict__ bih1,
    const float* __restrict__ Wih2, const float* __restrict__ bih2,
    const float* __restrict__ Wih3, const float* __restrict__ bih3,
    float* __restrict__ gi)
{
    __shared__ float As[BK][TM + 1];
    __shared__ float Bs[BK][TN + 1];
    __shared__ int   rows[TM];

    const int blocks_t = S_LEN / TM;   // 16
    const int blocks_j = G3 / TN;      // 24
    int b   = blockIdx.x;
    int p   = b / (blocks_t * blocks_j);
    int rem = b % (blocks_t * blocks_j);
    int bt  = rem / blocks_j;
    int bj  = rem % blocks_j;

    const float* Wih = (p == 0) ? Wih0 : (p == 1) ? Wih1 : (p == 2) ? Wih2 : Wih3;
    const float* bih = (p == 0) ? bih0 : (p == 1) ? bih1 : (p == 2) ? bih2 : bih3;

    int tid = threadIdx.x;
    if (tid < TM) rows[tid] = sent[bt * TM + tid];
    __syncthreads();

    int tt = (tid >> 4) * 4;   // local t offset of micro-tile
    int jj = (tid & 15) * 4;   // local j offset of micro-tile
    float acc[4][4] = {{0.f}};

    int lr = tid >> 2;         // 0..63 (row within tile)
    int lc = (tid & 3) * 8;    // 0,8,16,24 (col chunk)

    for (int k0 = 0; k0 < E_DIM; k0 += BK) {
        const float* asrc = emb + (size_t)rows[lr] * E_DIM + (k0 + lc);
        float4 a0 = *(const float4*)asrc;
        float4 a1 = *(const float4*)(asrc + 4);
        const float* bsrc = Wih + (size_t)(bj * TN + lr) * E_DIM + (k0 + lc);
        float4 b0 = *(const float4*)bsrc;
        float4 b1 = *(const float4*)(bsrc + 4);

        As[lc+0][lr]=a0.x; As[lc+1][lr]=a0.y; As[lc+2][lr]=a0.z; As[lc+3][lr]=a0.w;
        As[lc+4][lr]=a1.x; As[lc+5][lr]=a1.y; As[lc+6][lr]=a1.z; As[lc+7][lr]=a1.w;
        Bs[lc+0][lr]=b0.x; Bs[lc+1][lr]=b0.y; Bs[lc+2][lr]=b0.z; Bs[lc+3][lr]=b0.w;
        Bs[lc+4][lr]=b1.x; Bs[lc+5][lr]=b1.y; Bs[lc+6][lr]=b1.z; Bs[lc+7][lr]=b1.w;
        __syncthreads();

        #pragma unroll
        for (int kk = 0; kk < BK; ++kk) {
            float av[4], bv[4];
            #pragma unroll
            for (int e = 0; e < 4; ++e) { av[e] = As[kk][tt+e]; bv[e] = Bs[kk][jj+e]; }
            #pragma unroll
            for (int i = 0; i < 4; ++i)
                #pragma unroll
                for (int j2 = 0; j2 < 4; ++j2)
                    acc[i][j2] = fmaf(av[i], bv[j2], acc[i][j2]);
        }
        __syncthreads();
    }

    float* gout = gi + (size_t)p * S_LEN * G3;
    int jbase = bj * TN + jj;
    float bb0 = bih[jbase+0], bb1 = bih[jbase+1], bb2 = bih[jbase+2], bb3 = bih[jbase+3];
    #pragma unroll
    for (int i = 0; i < 4; ++i) {
        int t = bt * TM + tt + i;
        float4 v = make_float4(acc[i][0]+bb0, acc[i][1]+bb1, acc[i][2]+bb2, acc[i][3]+bb3);
        *(float4*)(gout + (size_t)t * G3 + jbase) = v;
    }
}

// ---------------------------------------------------------------------------
// Phase 2: 4 independent GRU recurrences, persistent kernel, FENCE-FREE sync.
//
// h exchange: hpk[c][parity][i] is a 64-bit slot {tag:u32 = step, val:f32}.
// Writers publish with relaxed agent-scope 64-bit atomic stores (sc0 sc1 --
// bypass L1/L2, no buffer_wbl2). Readers poll with relaxed agent-scope loads
// (no buffer_inv). Tag rides atomically with the value, so no flag counter
// and no fences are needed. Double-buffer by step parity + exact-tag match
// is race-free: a writer overwrites h_{s-2} only after having consumed every
// block's h_{s-1}, which implies all blocks finished reading h_{s-2}.
// 0xAA poison gives tag 0xAAAAAAAA which never matches s in [1,1024].
//
// Block b: chain c = b/32, sub-id w = b%32. Block owns h indices
// [16w,16w+16); wave wv computes 4 of them (lane<4). Whh rows for the
// block's outputs live in registers (96 floats/thread).
// ---------------------------------------------------------------------------
__global__ __launch_bounds__(256) void gru_scan_kernel(
    const float* __restrict__ Whh0, const float* __restrict__ bhh0,
    const float* __restrict__ Whh1, const float* __restrict__ bhh1,
    const float* __restrict__ Whh2, const float* __restrict__ bhh2,
    const float* __restrict__ Whh3, const float* __restrict__ bhh3,
    const float* __restrict__ gi,
    u64* __restrict__ hpk)             // [4][2][512] {tag,val} slots
{
    __shared__ float lds_h[2][H_DIM];

    int b = blockIdx.x;
    int c = b / WPC;
    int w = b % WPC;
    const float* Whh = (c==0)?Whh0:(c==1)?Whh1:(c==2)?Whh2:Whh3;
    const float* bhh = (c==0)?bhh0:(c==1)?bhh1:(c==2)?bhh2:bhh3;
    const float* gic = gi + (size_t)c * S_LEN * G3;
    u64* hp = hpk + (size_t)c * 2 * H_DIM;
    const bool fwd = ((c & 1) == 0);   // chains 0 (ctx_f) and 2 (qry_f) are forward

    int tid  = threadIdx.x;
    int wv   = tid >> 6;
    int lane = tid & 63;
    int base_i = w * 16 + wv * 4;

    // Load Whh fragment: wreg[g][m][e] = Whh[g*512 + base_i + m][lane*8 + e]
    float wreg[3][4][8];
    #pragma unroll
    for (int g = 0; g < 3; ++g)
        #pragma unroll
        for (int m = 0; m < 4; ++m) {
            const float* src = Whh + (size_t)(g * H_DIM + base_i + m) * H_DIM + lane * 8;
            float4 v0 = *(const float4*)src;
            float4 v1 = *(const float4*)(src + 4);
            wreg[g][m][0]=v0.x; wreg[g][m][1]=v0.y; wreg[g][m][2]=v0.z; wreg[g][m][3]=v0.w;
            wreg[g][m][4]=v1.x; wreg[g][m][5]=v1.y; wreg[g][m][6]=v1.z; wreg[g][m][7]=v1.w;
        }

    int my_i = base_i + lane;   // meaningful for lane < 4
    float bh_r=0.f, bh_z=0.f, bh_n=0.f;
    float gr=0.f, gz=0.f, gn=0.f;
    if (lane < 4) {
        bh_r = bhh[my_i]; bh_z = bhh[H_DIM + my_i]; bh_n = bhh[2*H_DIM + my_i];
        int t0 = fwd ? 0 : (S_LEN - 1);
        const float* g0 = gic + (size_t)t0 * G3;
        gr = g0[my_i]; gz = g0[H_DIM + my_i]; gn = g0[2*H_DIM + my_i];
    }

    // h_0 = 0 lives in LDS buffer 0.
    lds_h[0][tid]       = 0.f;
    lds_h[0][tid + 256] = 0.f;

    // Each thread is responsible for ferrying slots tid and tid+256.
    int s0 = tid, s1 = tid + 256;
    bool own0 = ((s0 >> 4) == w);
    bool own1 = ((s1 >> 4) == w);

    for (int s = 0; s < S_LEN; ++s) {
        int pb = s & 1;
        if (s > 0) {
            const u64* src = hp + (size_t)pb * H_DIM;
            bool p0 = own0, p1 = own1;
            while (!(p0 && p1)) {
                if (!p0) {
                    u64 v = __hip_atomic_load(src + s0, __ATOMIC_RELAXED, __HIP_MEMORY_SCOPE_AGENT);
                    if ((unsigned)(v >> 32) == (unsigned)s) {
                        lds_h[pb][s0] = __uint_as_float((unsigned)v);
                        p0 = true;
                    }
                }
                if (!p1) {
                    u64 v = __hip_atomic_load(src + s1, __ATOMIC_RELAXED, __HIP_MEMORY_SCOPE_AGENT);
                    if ((unsigned)(v >> 32) == (unsigned)s) {
                        lds_h[pb][s1] = __uint_as_float((unsigned)v);
                        p1 = true;
                    }
                }
            }
        }
        __syncthreads();

        float hf[8];
        #pragma unroll
        for (int e = 0; e < 8; ++e) hf[e] = lds_h[pb][lane * 8 + e];

        float acc[3][4];
        #pragma unroll
        for (int g = 0; g < 3; ++g)
            #pragma unroll
            for (int m = 0; m < 4; ++m) {
                float a = 0.f;
                #pragma unroll
                for (int e = 0; e < 8; ++e) a = fmaf(wreg[g][m][e], hf[e], a);
                acc[g][m] = a;
            }
        #pragma unroll
        for (int off = 32; off >= 1; off >>= 1)
            #pragma unroll
            for (int g = 0; g < 3; ++g)
                #pragma unroll
                for (int m = 0; m < 4; ++m)
                    acc[g][m] += __shfl_xor(acc[g][m], off, 64);

        if (lane < 4) {
            float ar = (lane==0)?acc[0][0]:(lane==1)?acc[0][1]:(lane==2)?acc[0][2]:acc[0][3];
            float az = (lane==0)?acc[1][0]:(lane==1)?acc[1][1]:(lane==2)?acc[1][2]:acc[1][3];
            float an = (lane==0)?acc[2][0]:(lane==1)?acc[2][1]:(lane==2)?acc[2][2]:acc[2][3];
            float hv = lds_h[pb][my_i];
            float rr = 1.f / (1.f + expf(-(gr + ar + bh_r)));
            float zz = 1.f / (1.f + expf(-(gz + az + bh_z)));
            float nn = tanhf(gn + rr * (an + bh_n));
            float hn = (1.f - zz) * nn + zz * hv;
            // Own value short-circuits through LDS for this block...
            lds_h[pb ^ 1][my_i] = hn;
            // ...and is published device-wide with the step tag riding along.
            union { float f; unsigned u; } cv; cv.f = hn;
            u64 pk = ((u64)(unsigned)(s + 1) << 32) | (u64)cv.u;
            __hip_atomic_store(hp + (size_t)(pb ^ 1) * H_DIM + my_i, pk,
                               __ATOMIC_RELAXED, __HIP_MEMORY_SCOPE_AGENT);
        }
        // Prefetch next step's gi (independent of recurrence — off critical path)
        if (lane < 4 && s + 1 < S_LEN) {
            int tn = fwd ? (s + 1) : (S_LEN - 2 - s);
            const float* gnx = gic + (size_t)tn * G3;
            gr = gnx[my_i]; gz = gnx[H_DIM + my_i]; gn = gnx[2*H_DIM + my_i];
        }
    }
}

// ---------------------------------------------------------------------------
// Phase 3a: h1 = relu(d1_w @ rep + d1_b); rep[j] = val(hpk[j>>9][0][j&511])
// (final h_1024 sits in parity-0 slots, tag 1024). One wave per output row.
// ---------------------------------------------------------------------------
__global__ __launch_bounds__(256) void dense1_kernel(
    const float* __restrict__ d1w, const float* __restrict__ d1b,
    const u64* __restrict__ hpk, float* __restrict__ h1)
{
    int wv = threadIdx.x >> 6, lane = threadIdx.x & 63;
    int row = blockIdx.x * 4 + wv;
    const float* wr = d1w + (size_t)row * (4 * H_DIM);
    float sum = 0.f;
    #pragma unroll
    for (int q = 0; q < 32; ++q) {
        int j = lane + q * 64;
        int cc = j >> 9;
        float h = __uint_as_float((unsigned)hpk[(size_t)cc * 2 * H_DIM + (j & 511)]);
        sum = fmaf(wr[j], h, sum);
    }
    #pragma unroll
    for (int off = 32; off >= 1; off >>= 1) sum += __shfl_xor(sum, off, 64);
    if (lane == 0) h1[row] = fmaxf(sum + d1b[row], 0.f);
}

// Phase 3b: out = sigmoid(d2_w @ h1 + d2_b), one block.
__global__ __launch_bounds__(256) void dense2_kernel(
    const float* __restrict__ d2w, const float* __restrict__ d2b,
    const float* __restrict__ h1, float* __restrict__ out)
{
    __shared__ float red[4];
    int tid = threadIdx.x, lane = tid & 63, wv = tid >> 6;
    float sum = 0.f;
    #pragma unroll
    for (int q = 0; q < 4; ++q) { int j = tid + q * 256; sum = fmaf(d2w[j], h1[j], sum); }
    #pragma unroll
    for (int off = 32; off >= 1; off >>= 1) sum += __shfl_xor(sum, off, 64);
    if (lane == 0) red[wv] = sum;
    __syncthreads();
    if (tid == 0) {
        float t = red[0] + red[1] + red[2] + red[3] + d2b[0];
        out[0] = 1.f / (1.f + expf(-t));
    }
}

// ---------------------------------------------------------------------------
extern "C" void kernel_launch(void* const* d_in, const int* in_sizes, int n_in,
                              void* d_out, int out_size, void* d_ws, size_t ws_size,
                              hipStream_t stream) {
    const int*   sent = (const int*)d_in[0];
    const float* emb  = (const float*)d_in[1];
    const float* Wih[4], *Whh[4], *bih[4], *bhh[4];
    for (int p = 0; p < 4; ++p) {
        Wih[p] = (const float*)d_in[2 + 4*p + 0];
        Whh[p] = (const float*)d_in[2 + 4*p + 1];
        bih[p] = (const float*)d_in[2 + 4*p + 2];
        bhh[p] = (const float*)d_in[2 + 4*p + 3];
    }
    const float* d1w = (const float*)d_in[18];
    const float* d1b = (const float*)d_in[19];
    const float* d2w = (const float*)d_in[20];
    const float* d2b = (const float*)d_in[21];
    float* out = (float*)d_out;

    // Workspace layout:
    //   gi    : 4*1024*1536 floats = 25165824 B
    //   hpk   : 4*2*512 u64        = 32768 B   (self-tagged; no init needed,
    //                                           0xAA poison never matches a tag)
    //   h1    : 1024 floats
    float* gi  = (float*)d_ws;
    u64*   hpk = (u64*)((char*)d_ws + (size_t)NCHAIN * S_LEN * G3 * sizeof(float));
    float* h1  = (float*)((char*)hpk + (size_t)NCHAIN * 2 * H_DIM * sizeof(u64));

    gi_gemm_kernel<<<NCHAIN * (S_LEN/TM) * (G3/TN), 256, 0, stream>>>(
        sent, emb,
        Wih[0], bih[0], Wih[1], bih[1], Wih[2], bih[2], Wih[3], bih[3], gi);

    gru_scan_kernel<<<NCHAIN * WPC, 256, 0, stream>>>(
        Whh[0], bhh[0], Whh[1], bhh[1], Whh[2], bhh[2], Whh[3], bhh[3],
        gi, hpk);

    dense1_kernel<<<D_DIM / 4, 256, 0, stream>>>(d1w, d1b, hpk, h1);
    dense2_kernel<<<1, 256, 0, stream>>>(d2w, d2b, h1, out);
}